// Round 2
// baseline (548.651 us; speedup 1.0000x reference)
//
#include <hip/hip_runtime.h>
#include <math.h>

#define NB 256
#define TT 4096
#define HH 32
#define CH 64   // timestep chunk: obuf columns, x-vector window

#if __has_builtin(__builtin_amdgcn_exp2f)
#define EXP2F(x) __builtin_amdgcn_exp2f(x)
#else
#define EXP2F(x) exp2f(x)
#endif

__device__ __forceinline__ float rlane(float v, int l) {
    return __uint_as_float(__builtin_amdgcn_readlane(__float_as_uint(v), l));
}

// One wave per batch element. The recurrent chain is kept ENTIRELY on the
// VALU pipe: h lives in registers (lane l holds h[l&31]; halves duplicate),
// and the per-step broadcast of all 32 h values is done with v_readlane into
// SGPRs, which then feed v_fma as the (single allowed) scalar operand.
// No DS-pipe op is on the critical chain (previous version paid ~240 cyc/step
// in LDS round-trip + shfl latency). tanh folded to exp2/rcp with the
// 2*log2(e) factor pre-scaled into W_hh / W_ih / biases.
// Per-step h is stashed in LDS (stride-65, conflict-free, write-only on the
// chain) and the W_fc dot over 64 steps is reduced in parallel across lanes.
__global__ __launch_bounds__(64, 1) void rnn_fused(
    const float* __restrict__ x,      // [B,T] (I==1)
    const float* __restrict__ W_ih,   // [H,1]
    const float* __restrict__ W_hh,   // [H,H]
    const float* __restrict__ b_ih,   // [H]
    const float* __restrict__ b_hh,   // [H]
    const float* __restrict__ W_fc,   // [1,H]
    const float* __restrict__ b_fc,   // [1]
    float* __restrict__ out)          // [B,T]
{
    const int lane = threadIdx.x;   // 0..63
    const int h    = lane & 31;
    const int b    = blockIdx.x;

    __shared__ float obuf[64 * 65];   // [row=lane][col=tc], stride 65 floats

    const float KAPPA = 2.8853900817779268f;  // 2 * log2(e)

    // full W_hh row h (both halves duplicate), pre-scaled by KAPPA
    float W2[HH];
#pragma unroll
    for (int r = 0; r < HH; ++r)
        W2[r] = KAPPA * W_hh[h * HH + r];

    const float wih  = KAPPA * W_ih[h];
    const float bias = KAPPA * (b_ih[h] + b_hh[h]);
    const float bfc  = b_fc[0];

    float wfc_r[HH];
#pragma unroll
    for (int r = 0; r < HH; ++r) wfc_r[r] = W_fc[r];

    const size_t xbase = (size_t)b * TT;
    float xv   = x[xbase + lane];   // x values for chunk 0
    float hcur = 0.0f;              // h[lane&31]

    for (int c = 0; c < TT / CH; ++c) {
        const int cn = (c + 1) & (TT / CH - 1);      // wrapped prefetch
        float xv_next = x[xbase + cn * CH + lane];

#pragma unroll 8
        for (int tc = 0; tc < CH; ++tc) {
            // this step's scalar input -> SGPR
            float sx = rlane(xv, tc);

            // broadcast all 32 h values into SGPRs (VALU pipe, no DS latency)
            float sh[HH];
#pragma unroll
            for (int k = 0; k < HH; ++k) sh[k] = rlane(hcur, k);

            float a0 = fmaf(wih, sx, bias);
            float a1 = 0.0f, a2 = 0.0f, a3 = 0.0f;
#pragma unroll
            for (int k = 0; k < HH; k += 4) {
                a0 = fmaf(W2[k + 0], sh[k + 0], a0);
                a1 = fmaf(W2[k + 1], sh[k + 1], a1);
                a2 = fmaf(W2[k + 2], sh[k + 2], a2);
                a3 = fmaf(W2[k + 3], sh[k + 3], a3);
            }
            float dot = (a0 + a1) + (a2 + a3);

            // h = tanh(a) = 1 - 2/(1 + 2^(2*log2e*a)); scaling pre-folded
            float e = EXP2F(dot);
            hcur = fmaf(-2.0f, __builtin_amdgcn_rcpf(e + 1.0f), 1.0f);

            obuf[lane * 65 + tc] = hcur;   // stash (write-only on the chain)
        }

        // parallel W_fc reduction: lane t computes sum_h obuf[h][t] * wfc[h]
        __builtin_amdgcn_wave_barrier();
        float s0 = 0.0f, s1 = 0.0f, s2 = 0.0f, s3 = 0.0f;
#pragma unroll
        for (int r = 0; r < HH; r += 4) {
            s0 = fmaf(obuf[(r + 0) * 65 + lane], wfc_r[r + 0], s0);
            s1 = fmaf(obuf[(r + 1) * 65 + lane], wfc_r[r + 1], s1);
            s2 = fmaf(obuf[(r + 2) * 65 + lane], wfc_r[r + 2], s2);
            s3 = fmaf(obuf[(r + 3) * 65 + lane], wfc_r[r + 3], s3);
        }
        out[xbase + c * CH + lane] = (s0 + s1) + (s2 + s3) + bfc;

        xv = xv_next;
        __builtin_amdgcn_wave_barrier();
    }
}

extern "C" void kernel_launch(void* const* d_in, const int* in_sizes, int n_in,
                              void* d_out, int out_size, void* d_ws, size_t ws_size,
                              hipStream_t stream) {
    const float* x    = (const float*)d_in[0];
    const float* W_ih = (const float*)d_in[1];
    const float* W_hh = (const float*)d_in[2];
    const float* b_ih = (const float*)d_in[3];
    const float* b_hh = (const float*)d_in[4];
    const float* W_fc = (const float*)d_in[5];
    const float* b_fc = (const float*)d_in[6];
    float* out = (float*)d_out;

    rnn_fused<<<NB, 64, 0, stream>>>(x, W_ih, W_hh, b_ih, b_hh, W_fc, b_fc, out);
}

// Round 4
// 449.413 us; speedup vs baseline: 1.2208x; 1.2208x over previous
//
#include <hip/hip_runtime.h>
#include <math.h>

#define NB 256
#define TT 4096
#define HH 32
#define CH 64   // timestep chunk: obuf columns, x-vector window

typedef float f32x2 __attribute__((ext_vector_type(2)));

#if __has_builtin(__builtin_amdgcn_exp2f)
#define EXP2F(x) __builtin_amdgcn_exp2f(x)
#else
#define EXP2F(x) exp2f(x)
#endif

__device__ __forceinline__ float rlane(float v, int l) {
    return __uint_as_float(__builtin_amdgcn_readlane(__float_as_uint(v), l));
}

// Packed fp32 math (gfx90a+/CDNA4): one instruction = 2 f32 FMAs.
__device__ __forceinline__ f32x2 pk_fma(f32x2 a, f32x2 b, f32x2 c) {
    f32x2 d;
    asm("v_pk_fma_f32 %0, %1, %2, %3" : "=v"(d) : "v"(a), "v"(b), "v"(c));
    return d;
}
__device__ __forceinline__ f32x2 pk_add(f32x2 a, f32x2 b) {
    f32x2 d;
    asm("v_pk_add_f32 %0, %1, %2" : "=v"(d) : "v"(a), "v"(b));
    return d;
}

// One wave per batch. Recurrent chain has exactly ONE DS hop per step:
//   dot -> exp2 -> rcp -> ds_write r -> (next step) broadcast ds_read r
// Each lane computes the FULL 32-wide dot for output j=lane&31 (halves
// duplicate) with 16 v_pk_fma_f32. We broadcast r = 1/(1+e^{2a}) instead of
// h = tanh(a): h = 1 - 2r is folded into the weights (W3 = -2*kappa*W_hh,
// row-sums into the bias, -2*W_fc into the output reduction), so neither the
// chain nor the epilogue ever materializes h.
__global__ __launch_bounds__(64, 1) void rnn_fused(
    const float* __restrict__ x,      // [B,T] (I==1)
    const float* __restrict__ W_ih,   // [H,1]
    const float* __restrict__ W_hh,   // [H,H]
    const float* __restrict__ b_ih,   // [H]
    const float* __restrict__ b_hh,   // [H]
    const float* __restrict__ W_fc,   // [1,H]
    const float* __restrict__ b_fc,   // [1]
    float* __restrict__ out)          // [B,T]
{
    const int lane = threadIdx.x;   // 0..63
    const int j    = lane & 31;
    const int b    = blockIdx.x;

    __shared__ __align__(16) float r_lds[64];  // r vector; only [0..31] read
    __shared__ float obuf[64 * 65];            // r history, stride-65 rows

    const float KAPPA = 2.8853900817779268f;  // 2 * log2(e)

    // W3[k] = -2*kappa*W_hh[j][k]; rowsum folds h=1-2r into the bias
    f32x2 W3[16];
    float rowsum = 0.0f;
#pragma unroll
    for (int k = 0; k < HH; ++k) {
        float w = W_hh[j * HH + k];
        rowsum += w;
        W3[k >> 1][k & 1] = -2.0f * KAPPA * w;
    }
    const float wih   = KAPPA * W_ih[j];
    const float bias2 = KAPPA * (b_ih[j] + b_hh[j] + rowsum);

    // epilogue constants: y = (bfc + sum wfc) + sum_j (-2*wfc[j]) * r[j]
    float wfcm[HH];
    float sum_wfc = 0.0f;
#pragma unroll
    for (int r = 0; r < HH; ++r) {
        float w = W_fc[r];
        sum_wfc += w;
        wfcm[r] = -2.0f * w;
    }
    const float bfc2 = b_fc[0] + sum_wfc;

    r_lds[lane] = 0.5f;   // h=0  <=>  r=0.5
    __syncthreads();

    const size_t xbase = (size_t)b * TT;
    float xv = x[xbase + lane];

    const f32x2* RP = (const f32x2*)r_lds;   // 16 pairs, broadcast reads

    for (int c = 0; c < TT / CH; ++c) {
        const int cn = (c + 1) & (TT / CH - 1);      // wrapped prefetch
        float xv_next = x[xbase + cn * CH + lane];

#pragma unroll 8
        for (int tc = 0; tc < CH; ++tc) {
            float sx   = rlane(xv, tc);              // uniform index
            float base = fmaf(wih, sx, bias2);

            // broadcast-read all 32 r values (conflict-free, one DS hop)
            f32x2 rr[16];
#pragma unroll
            for (int i = 0; i < 16; ++i) rr[i] = RP[i];

            f32x2 a0 = {0.0f, 0.0f}, a1 = a0, a2 = a0, a3 = a0;
#pragma unroll
            for (int i = 0; i < 16; i += 4) {
                a0 = pk_fma(W3[i + 0], rr[i + 0], a0);
                a1 = pk_fma(W3[i + 1], rr[i + 1], a1);
                a2 = pk_fma(W3[i + 2], rr[i + 2], a2);
                a3 = pk_fma(W3[i + 3], rr[i + 3], a3);
            }
            f32x2 t = pk_add(pk_add(a0, a1), pk_add(a2, a3));
            float dot = base + (t.x + t.y);          // = 2*log2e * preact

            float e    = EXP2F(dot);
            float rnew = __builtin_amdgcn_rcpf(e + 1.0f);  // r in (0,1)

            r_lds[lane]          = rnew;   // next step's broadcast source
            obuf[lane * 65 + tc] = rnew;   // stash for W_fc epilogue
        }

        // lane t: y_t = bfc2 + sum_j wfcm[j] * r_t[j]
        __builtin_amdgcn_wave_barrier();
        float s0 = 0.0f, s1 = 0.0f, s2 = 0.0f, s3 = 0.0f;
#pragma unroll
        for (int r = 0; r < HH; r += 4) {
            s0 = fmaf(obuf[(r + 0) * 65 + lane], wfcm[r + 0], s0);
            s1 = fmaf(obuf[(r + 1) * 65 + lane], wfcm[r + 1], s1);
            s2 = fmaf(obuf[(r + 2) * 65 + lane], wfcm[r + 2], s2);
            s3 = fmaf(obuf[(r + 3) * 65 + lane], wfcm[r + 3], s3);
        }
        out[xbase + c * CH + lane] = (s0 + s1) + (s2 + s3) + bfc2;

        xv = xv_next;
        __builtin_amdgcn_wave_barrier();
    }
}

extern "C" void kernel_launch(void* const* d_in, const int* in_sizes, int n_in,
                              void* d_out, int out_size, void* d_ws, size_t ws_size,
                              hipStream_t stream) {
    const float* x    = (const float*)d_in[0];
    const float* W_ih = (const float*)d_in[1];
    const float* W_hh = (const float*)d_in[2];
    const float* b_ih = (const float*)d_in[3];
    const float* b_hh = (const float*)d_in[4];
    const float* W_fc = (const float*)d_in[5];
    const float* b_fc = (const float*)d_in[6];
    float* out = (float*)d_out;

    rnn_fused<<<NB, 64, 0, stream>>>(x, W_ih, W_hh, b_ih, b_hh, W_fc, b_fc, out);
}

// Round 6
// 386.838 us; speedup vs baseline: 1.4183x; 1.1618x over previous
//
#include <hip/hip_runtime.h>
#include <math.h>

#define NB 256
#define TT 4096
#define HH 32
#define CH 64   // timestep chunk: obuf columns, x-vector window

#if __has_builtin(__builtin_amdgcn_exp2f)
#define EXP2F(x) __builtin_amdgcn_exp2f(x)
#else
#define EXP2F(x) exp2f(x)
#endif

__device__ __forceinline__ float rlane(float v, int l) {
    return __uint_as_float(__builtin_amdgcn_readlane(__float_as_uint(v), l));
}

// One wave per batch; recurrent chain is 100% VALU-pipe (no DS ops).
// 32x32 matvec via DPP row-rotation systolic dot:
//   rows (16 lanes): row0=(out 0-15, kh=0), row1=(out 16-31, kh=1),
//                    row2=(out 0-15, kh=1), row3=(out 16-31, kh=0)
//   lane holds r[16*kh + i16]; 16 v_fmac_f32_dpp row_ror:d accumulate the
//   16-term partial. Cross-half combine: v_permlane32_swap (sum of both
//   outputs -> direction-independent). Next-step layout: v_permlane16_swap.
// DIRECTION CALIBRATION (the R4 bug): both the row_ror receive direction and
// the permlane16_swap output assignment are probed in the prologue with an
// identity pattern, so the kernel is correct under either HW convention.
// We iterate r = 1/(1+e^{2a}); h = 1-2r is folded into weights/bias/W_fc.
__global__ __launch_bounds__(64, 1) void rnn_fused(
    const float* __restrict__ x,      // [B,T] (I==1)
    const float* __restrict__ W_ih,   // [H,1]
    const float* __restrict__ W_hh,   // [H,H]
    const float* __restrict__ b_ih,   // [H]
    const float* __restrict__ b_hh,   // [H]
    const float* __restrict__ W_fc,   // [1,H]
    const float* __restrict__ b_fc,   // [1]
    float* __restrict__ out)          // [B,T]
{
    const int lane = threadIdx.x;   // 0..63
    const int i16  = lane & 15;
    const int R    = lane >> 4;          // DPP row 0..3
    const int j    = lane & 31;          // output index this lane computes
    const int kh   = (R ^ (R >> 1)) & 1; // K-half: rows 0,3 -> 0; 1,2 -> 1

    __shared__ float obuf[64 * 65];   // r history, stride-65 rows

    const float KAPPA = 2.8853900817779268f;  // 2 * log2(e)

    // --- calibration probe 1: row_ror receive direction ---
    int rr;
    asm volatile("s_nop 1\n\t"
                 "v_mov_b32_dpp %0, %1 row_ror:1 row_mask:0xf bank_mask:0xf"
                 : "=v"(rr) : "v"(lane));
    const int rsign = ((rr & 15) == ((i16 + 1) & 15)) ? 1 : -1;

    // --- calibration probe 2: permlane16_swap output assignment ---
    int va = lane, vb = lane;
    asm volatile("s_nop 1\n\t"
                 "v_permlane16_swap_b32 %0, %1" : "+v"(va), "+v"(vb));
    const int  tgt  = kh * 16 + i16;          // lane index whose r we need
    const bool useA = ((va & 31) == tgt);     // else use the second output

    float rowsum = 0.0f;
#pragma unroll
    for (int k = 0; k < HH; ++k) rowsum += W_hh[j * HH + k];

    // rotation-ordered weights: at row_ror:d this lane receives
    // r[16*kh + ((i16 + rsign*d)&15)], so pair it with that W column.
    float Wd[16];
#pragma unroll
    for (int d = 0; d < 16; ++d)
        Wd[d] = -2.0f * KAPPA * W_hh[j * HH + kh * 16 + ((i16 + rsign * d) & 15)];

    // halved: lane and its +-32 partner both seed base; sum gives it once
    const float wihH  = 0.5f * KAPPA * W_ih[j];
    const float biasH = 0.5f * KAPPA * (b_ih[j] + b_hh[j] + rowsum);

    float wfcm[HH];
    float sum_wfc = 0.0f;
#pragma unroll
    for (int r = 0; r < HH; ++r) {
        float w = W_fc[r];
        sum_wfc += w;
        wfcm[r] = -2.0f * w;
    }
    const float bfc2 = b_fc[0] + sum_wfc;

    const size_t xbase = (size_t)blockIdx.x * TT;
    float xv = x[xbase + lane];
    float rv = 0.5f;                  // h=0 <=> r=0.5 (layout-independent)

    for (int c = 0; c < TT / CH; ++c) {
        const int cn = (c + 1) & (TT / CH - 1);      // wrapped prefetch
        float xv_next = x[xbase + cn * CH + lane];

#pragma unroll 8
        for (int tc = 0; tc < CH; ++tc) {
            float sx   = rlane(xv, tc);
            float acc0 = fmaf(wihH, sx, biasH);
            float acc1 = 0.0f, acc2 = 0.0f, acc3 = 0.0f;

            // 16-term systolic partial dot; s_nop guards VALU->DPP hazard
            asm("s_nop 1\n\t"
                "v_fmac_f32 %0, %4, %5\n\t"
                "v_fmac_f32_dpp %1, %4, %6 row_ror:1 row_mask:0xf bank_mask:0xf\n\t"
                "v_fmac_f32_dpp %2, %4, %7 row_ror:2 row_mask:0xf bank_mask:0xf\n\t"
                "v_fmac_f32_dpp %3, %4, %8 row_ror:3 row_mask:0xf bank_mask:0xf\n\t"
                "v_fmac_f32_dpp %0, %4, %9 row_ror:4 row_mask:0xf bank_mask:0xf\n\t"
                "v_fmac_f32_dpp %1, %4, %10 row_ror:5 row_mask:0xf bank_mask:0xf\n\t"
                "v_fmac_f32_dpp %2, %4, %11 row_ror:6 row_mask:0xf bank_mask:0xf\n\t"
                "v_fmac_f32_dpp %3, %4, %12 row_ror:7 row_mask:0xf bank_mask:0xf\n\t"
                "v_fmac_f32_dpp %0, %4, %13 row_ror:8 row_mask:0xf bank_mask:0xf\n\t"
                "v_fmac_f32_dpp %1, %4, %14 row_ror:9 row_mask:0xf bank_mask:0xf\n\t"
                "v_fmac_f32_dpp %2, %4, %15 row_ror:10 row_mask:0xf bank_mask:0xf\n\t"
                "v_fmac_f32_dpp %3, %4, %16 row_ror:11 row_mask:0xf bank_mask:0xf\n\t"
                "v_fmac_f32_dpp %0, %4, %17 row_ror:12 row_mask:0xf bank_mask:0xf\n\t"
                "v_fmac_f32_dpp %1, %4, %18 row_ror:13 row_mask:0xf bank_mask:0xf\n\t"
                "v_fmac_f32_dpp %2, %4, %19 row_ror:14 row_mask:0xf bank_mask:0xf\n\t"
                "v_fmac_f32_dpp %3, %4, %20 row_ror:15 row_mask:0xf bank_mask:0xf"
                : "+v"(acc0), "+v"(acc1), "+v"(acc2), "+v"(acc3)
                : "v"(rv),
                  "v"(Wd[0]),  "v"(Wd[1]),  "v"(Wd[2]),  "v"(Wd[3]),
                  "v"(Wd[4]),  "v"(Wd[5]),  "v"(Wd[6]),  "v"(Wd[7]),
                  "v"(Wd[8]),  "v"(Wd[9]),  "v"(Wd[10]), "v"(Wd[11]),
                  "v"(Wd[12]), "v"(Wd[13]), "v"(Wd[14]), "v"(Wd[15]));

            float p = (acc0 + acc1) + (acc2 + acc3);

            // cross-half combine: outputs are the two 32-half partials in
            // some order; their SUM is direction-independent.
            float u = p, w2 = p;
            asm("s_nop 1\n\t"
                "v_permlane32_swap_b32 %0, %1" : "+v"(u), "+v"(w2));
            float dot = u + w2;                         // full preact * kappa

            float e   = EXP2F(dot);
            float rnw = __builtin_amdgcn_rcpf(e + 1.0f);  // r in (0,1)

            // layout fixup: one output holds r_new[i16] bcast, the other
            // r_new[16+i16] bcast; calibrated select picks the right one.
            float fa = rnw, fb = rnw;
            asm("s_nop 2\n\t"
                "v_permlane16_swap_b32 %0, %1" : "+v"(fa), "+v"(fb));
            rv = useA ? fa : fb;

            obuf[lane * 65 + tc] = rnw;   // stash (DS pipe otherwise idle)
        }

        // lane t: y_t = bfc2 + sum_j wfcm[j] * r_t[j]  (rows 0..31 hold r_t)
        __builtin_amdgcn_wave_barrier();
        float s0 = 0.0f, s1 = 0.0f, s2 = 0.0f, s3 = 0.0f;
#pragma unroll
        for (int r = 0; r < HH; r += 4) {
            s0 = fmaf(obuf[(r + 0) * 65 + lane], wfcm[r + 0], s0);
            s1 = fmaf(obuf[(r + 1) * 65 + lane], wfcm[r + 1], s1);
            s2 = fmaf(obuf[(r + 2) * 65 + lane], wfcm[r + 2], s2);
            s3 = fmaf(obuf[(r + 3) * 65 + lane], wfcm[r + 3], s3);
        }
        out[xbase + c * CH + lane] = (s0 + s1) + (s2 + s3) + bfc2;

        xv = xv_next;
        __builtin_amdgcn_wave_barrier();
    }
}

extern "C" void kernel_launch(void* const* d_in, const int* in_sizes, int n_in,
                              void* d_out, int out_size, void* d_ws, size_t ws_size,
                              hipStream_t stream) {
    const float* x    = (const float*)d_in[0];
    const float* W_ih = (const float*)d_in[1];
    const float* W_hh = (const float*)d_in[2];
    const float* b_ih = (const float*)d_in[3];
    const float* b_hh = (const float*)d_in[4];
    const float* W_fc = (const float*)d_in[5];
    const float* b_fc = (const float*)d_in[6];
    float* out = (float*)d_out;

    rnn_fused<<<NB, 64, 0, stream>>>(x, W_ih, W_hh, b_ih, b_hh, W_fc, b_fc, out);
}